// Round 12
// baseline (686.707 us; speedup 1.0000x reference)
//
#include <hip/hip_runtime.h>
#include <stdint.h>

// ---- problem constants ----
#define D_MODEL  2048
#define N_INTER  1408
#define SH_INTER 2816
#define T_TOK    2048
#define NSLOT    (T_TOK * 4)
#define MIB(x)   ((size_t)(x) << 20)

typedef __attribute__((ext_vector_type(8))) short bf16x8;
typedef __attribute__((ext_vector_type(4))) float f32x4;

__device__ __forceinline__ unsigned short f2bf(float f){
  unsigned int b = __builtin_bit_cast(unsigned int, f);
  b = (b + 0x7FFFu + ((b >> 16) & 1u)) >> 16;   // RNE, finite inputs
  return (unsigned short)b;
}
__device__ __forceinline__ float bf2f(unsigned short h){
  unsigned int b = ((unsigned int)h) << 16;
  return __builtin_bit_cast(float, b);
}

// async global->LDS, 16B per lane; LDS dest = wave-uniform base + lane*16
#define GLOAD16(gp, lp) __builtin_amdgcn_global_load_lds( \
    (const __attribute__((address_space(1))) unsigned int*)(gp), \
    (__attribute__((address_space(3))) unsigned int*)(lp), 16, 0, 0)

// ---------------- fp32 -> bf16 streaming convert ----------------
__global__ void cvt_bf16_kernel(const float* __restrict__ x,
                                unsigned short* __restrict__ o, int n4){
  const int stride = gridDim.x * blockDim.x;
  for (int i = blockIdx.x * blockDim.x + threadIdx.x; i < n4; i += stride){
    const float4 v = ((const float4*)x)[i];
    ushort4 u; u.x = f2bf(v.x); u.y = f2bf(v.y); u.z = f2bf(v.z); u.w = f2bf(v.w);
    ((ushort4*)o)[i] = u;
  }
}

// ---------------- phase A: convert x + all shared-expert weights ----------------
// S1 and S3 are CONTIGUOUS (S3 = S1 + SH_INTER*D_MODEL) forming the G|U concat.
__global__ void cvt4_kernel(const float* __restrict__ x,  const float* __restrict__ Ws1,
                            const float* __restrict__ Ws3, const float* __restrict__ Ws2,
                            unsigned short* __restrict__ xbf, unsigned short* __restrict__ S1,
                            unsigned short* __restrict__ S3,  unsigned short* __restrict__ S2){
  const int N0 = T_TOK * D_MODEL / 4;
  const int NW = SH_INTER * D_MODEL / 4;
  const int total = N0 + 3 * NW;
  const int stride = gridDim.x * blockDim.x;
  for (int i = blockIdx.x * blockDim.x + threadIdx.x; i < total; i += stride){
    const float4* s; ushort4* d; int j;
    if (i < N0)            { s = (const float4*)x;   d = (ushort4*)xbf; j = i; }
    else if (i < N0 + NW)  { s = (const float4*)Ws1; d = (ushort4*)S1;  j = i - N0; }
    else if (i < N0 + 2*NW){ s = (const float4*)Ws3; d = (ushort4*)S3;  j = i - N0 - NW; }
    else                   { s = (const float4*)Ws2; d = (ushort4*)S2;  j = i - N0 - 2*NW; }
    const float4 v = s[j];
    ushort4 u; u.x = f2bf(v.x); u.y = f2bf(v.y); u.z = f2bf(v.z); u.w = f2bf(v.w);
    d[j] = u;
  }
}

// ---------------- gate: softmax + group-limited top-k ----------------
__global__ void gate_kernel(const float* __restrict__ x, const float* __restrict__ Wg,
                            int* __restrict__ cnt, int* __restrict__ list,
                            float* __restrict__ wslot){
  const int t = blockIdx.x;
  const int l = threadIdx.x;
  const int e = l & 15, q = l >> 4;
  const float* xr = x + (size_t)t * D_MODEL + q * 512;
  const float* wr = Wg + (size_t)e * D_MODEL + q * 512;
  float p = 0.f;
  #pragma unroll 4
  for (int i = 0; i < 512; i += 4){
    float4 xv = *(const float4*)(xr + i);
    float4 wv = *(const float4*)(wr + i);
    p += xv.x*wv.x + xv.y*wv.y + xv.z*wv.z + xv.w*wv.w;
  }
  p += __shfl_xor(p, 16);
  p += __shfl_xor(p, 32);
  float mx = p;
  for (int d = 1; d < 16; d <<= 1) mx = fmaxf(mx, __shfl_xor(mx, d));
  float ex = __expf(p - mx);
  float sum = ex;
  for (int d = 1; d < 16; d <<= 1) sum += __shfl_xor(sum, d);
  const float sc = ex / sum;
  float gm = fmaxf(sc, __shfl_xor(sc, 1));
  gm = fmaxf(gm, __shfl_xor(gm, 2));
  const float g0 = __shfl(gm, 0), g1 = __shfl(gm, 4),
              g2 = __shfl(gm, 8), g3 = __shfl(gm, 12);
  const int grp = e >> 2;
  const float gs[4] = {g0, g1, g2, g3};
  int grank = 0;
  #pragma unroll
  for (int j = 0; j < 4; ++j)
    if (gs[j] > gm || (gs[j] == gm && j < grp)) grank++;
  const float msc = (grank < 2) ? sc : -INFINITY;
  int erank = 0;
  #pragma unroll
  for (int j = 0; j < 16; ++j){
    const float oj = __shfl(msc, j);
    if (oj > msc || (oj == msc && j < e)) erank++;
  }
  if (q == 0 && erank < 4 && msc > -INFINITY){
    const int pos = atomicAdd(&cnt[e], 1);
    const int slot = (t << 2) | erank;
    list[e * T_TOK + pos] = slot;
    wslot[slot] = sc;            // ROUTE_SCALE = 1
  }
}

// ---- gemm6 (R6-proven, untouched): BM=128 BN=128 BK=32, 4 waves ----
// 3-deep pipeline, counted vmcnt(8/4/0), gload_lds + XOR swizzle (0 conflicts).
// MODE 0: linear A, bf16 out     MODE 1: linear A, fp32 out
template<int MODE>
__global__ __launch_bounds__(256, 3)
void gemm6_kernel(const unsigned short* __restrict__ A,
                  const unsigned short* __restrict__ B,
                  void* __restrict__ OutP,
                  int N, int K, int Astride, int MT, int NT)
{
  __shared__ unsigned short As[3 * 128 * 32];   // 24 KB
  __shared__ unsigned short Bs[3 * 128 * 32];   // 24 KB

  const int per = gridDim.x >> 3;
  const int gsw = (blockIdx.x & 7) * per + (blockIdx.x >> 3);
  const int mt   = gsw % MT;
  const int nt   = gsw / MT;

  const int tid = threadIdx.x, wid = tid >> 6, lane = tid & 63;
  const int rt0 = 32 * wid + (lane >> 2), rt1 = rt0 + 16;
  const int sxA = ((lane & 3) ^ ((lane >> 3) & 3)) << 3;   // shorts

  const int ar0 = mt * 128 + rt0, ar1 = mt * 128 + rt1;
  const unsigned short* pa0 = A + (size_t)ar0 * Astride + sxA;
  const unsigned short* pa1 = A + (size_t)ar1 * Astride + sxA;
  const unsigned short* pb0 = B + (size_t)(nt * 128 + rt0) * K + sxA;
  const unsigned short* pb1 = pb0 + (size_t)16 * K;

  const int aW0 = (32 * wid) * 32, aW1 = aW0 + 512;        // shorts
  const int bufStride = 128 * 32;

  const int wr = wid >> 1, wc = wid & 1, lr = lane & 15, lq = lane >> 4;
  const int fx = ((lq ^ ((lr >> 1) & 3)) << 3);
  int aoff[4], boff[4];
  #pragma unroll
  for (int m = 0; m < 4; ++m) aoff[m] = (wr * 64 + m * 16 + lr) * 32 + fx;
  #pragma unroll
  for (int n = 0; n < 4; ++n) boff[n] = (wc * 64 + n * 16 + lr) * 32 + fx;

  f32x4 acc[4][4];
  const f32x4 zero = {0.f, 0.f, 0.f, 0.f};
  #pragma unroll
  for (int m = 0; m < 4; ++m)
    #pragma unroll
    for (int n = 0; n < 4; ++n) acc[m][n] = zero;

  const int KT = K >> 5;
  #pragma unroll
  for (int t = 0; t < 3; ++t){
    GLOAD16(pa0, As + t * bufStride + aW0);
    GLOAD16(pa1, As + t * bufStride + aW1);
    GLOAD16(pb0, Bs + t * bufStride + aW0);
    GLOAD16(pb1, Bs + t * bufStride + aW1);
    pa0 += 32; pa1 += 32; pb0 += 32; pb1 += 32;
  }
  int c = 0;

  for (int kt = 0; kt < KT; ++kt){
    if (kt < KT - 2)       asm volatile("s_waitcnt vmcnt(8)" ::: "memory");
    else if (kt == KT - 2) asm volatile("s_waitcnt vmcnt(4)" ::: "memory");
    else                   asm volatile("s_waitcnt vmcnt(0)" ::: "memory");
    __builtin_amdgcn_s_barrier();

    const unsigned short* aC = As + c * bufStride;
    const unsigned short* bC = Bs + c * bufStride;
    bf16x8 af[4], bf[4];
    #pragma unroll
    for (int m = 0; m < 4; ++m) af[m] = *(const bf16x8*)(aC + aoff[m]);
    #pragma unroll
    for (int n = 0; n < 4; ++n) bf[n] = *(const bf16x8*)(bC + boff[n]);

    asm volatile("s_waitcnt lgkmcnt(0)" ::: "memory");
    __builtin_amdgcn_sched_barrier(0);
    __builtin_amdgcn_s_barrier();

    if (kt + 3 < KT){
      GLOAD16(pa0, As + c * bufStride + aW0);
      GLOAD16(pa1, As + c * bufStride + aW1);
      GLOAD16(pb0, Bs + c * bufStride + aW0);
      GLOAD16(pb1, Bs + c * bufStride + aW1);
      pa0 += 32; pa1 += 32; pb0 += 32; pb1 += 32;
    }

    #pragma unroll
    for (int n = 0; n < 4; ++n)
      #pragma unroll
      for (int m = 0; m < 4; ++m)
        acc[m][n] = __builtin_amdgcn_mfma_f32_16x16x32_bf16(af[m], bf[n], acc[m][n], 0, 0, 0);

    c = (c == 2) ? 0 : c + 1;
  }

  const int colBase = nt * 128 + wc * 64;
  #pragma unroll
  for (int m = 0; m < 4; ++m){
    #pragma unroll
    for (int r = 0; r < 4; ++r){
      const int grow = mt * 128 + wr * 64 + m * 16 + lq * 4 + r;
      if constexpr (MODE == 1){
        float* op = (float*)OutP + (size_t)grow * N + colBase;
        #pragma unroll
        for (int n = 0; n < 4; ++n) op[n * 16 + lr] = acc[m][n][r];
      } else {
        unsigned short* op = (unsigned short*)OutP + (size_t)grow * N + colBase;
        #pragma unroll
        for (int n = 0; n < 4; ++n) op[n * 16 + lr] = f2bf(acc[m][n][r]);
      }
    }
  }
}

// ==== gemmW: BM=256 x BN=128 x BK=32, 8 waves (4M x 2N), gathered routed GEMM ====
// Halves weight-stream bytes/FLOP vs 128^2 (B is the L3/HBM-bound stream).
// Same per-wave 64x64 / 16-MFMA inner loop; 3 gloads/wave/tile -> vmcnt 6/3/0.
// LDS 72 KB -> 2 blocks/CU, 16 waves/CU.
// MODE 2: A by token (entry>>2), dual-B panel select at NTH (G|U concat out, no straddle)
// MODE 3: A by slot (entry, strided), single B, bf16 out at slot
template<int MODE>
__global__ __launch_bounds__(512, 2)
void gemmW_kernel(const unsigned short* __restrict__ A,
                  const unsigned short* __restrict__ BG,
                  const unsigned short* __restrict__ BU,
                  unsigned short* __restrict__ Out,
                  const int* __restrict__ list,
                  const int* __restrict__ cnt,
                  int K, int N, int Astride, int NT, int NTH)
{
  __shared__ unsigned short As[3 * 8192];   // 48 KB (256x32/tile)
  __shared__ unsigned short Bs[3 * 4096];   // 24 KB (128x32/tile)
  const int MT = 8;

  const int per = gridDim.x >> 3;           // bijective XCD swizzle (grid%8==0)
  const int gsw = (blockIdx.x & 7) * per + (blockIdx.x >> 3);
  const int mt   = gsw % MT;
  const int rest = gsw / MT;
  const int nt = rest % NT;
  const int e  = rest / NT;
  const int cntE = cnt[e];
  if (mt * 256 >= cntE) return;

  const int tid = threadIdx.x, wid = tid >> 6, lane = tid & 63;
  const int sx = ((lane & 3) ^ ((lane >> 3) & 3)) << 3;    // src 16B-slot XOR, shorts

  // ---- A staging: wave w rows [32w,32w+32), 2 gloads x 16 rows ----
  const int rt0 = 32 * wid + (lane >> 2), rt1 = rt0 + 16;
  const int lim = cntE - 1;
  int p0 = mt * 256 + rt0; p0 = p0 < lim ? p0 : lim;
  int p1 = mt * 256 + rt1; p1 = p1 < lim ? p1 : lim;
  const int e0 = list[e * T_TOK + p0], e1 = list[e * T_TOK + p1];
  const int ar0 = (MODE == 2) ? (e0 >> 2) : e0;
  const int ar1 = (MODE == 2) ? (e1 >> 2) : e1;
  const unsigned short* pa0 = A + (size_t)ar0 * Astride + sx;
  const unsigned short* pa1 = A + (size_t)ar1 * Astride + sx;

  // ---- B staging: wave w rows [16w,16w+16), 1 gload ----
  const int rb = 16 * wid + (lane >> 2);
  const unsigned short* pb0;
  if (MODE == 2){
    const size_t eo = (size_t)e * N_INTER * K;
    const unsigned short* wsrc = (nt < NTH) ? BG : BU;
    const int rowoff = (nt < NTH) ? nt * 128 : (nt - NTH) * 128;
    pb0 = wsrc + eo + (size_t)(rowoff + rb) * K + sx;
  } else {
    pb0 = BG + (size_t)e * N * K + (size_t)(nt * 128 + rb) * K + sx;
  }

  const int aW0 = (32 * wid) * 32, aW1 = aW0 + 512;        // shorts
  const int bW  = (16 * wid) * 32;                         // shorts
  const int aStr = 8192, bStr = 4096;

  // ---- fragment read offsets (XOR-swizzled) ----
  const int wm = wid >> 1, wn = wid & 1, lr = lane & 15, lq = lane >> 4;
  const int fx = ((lq ^ ((lr >> 1) & 3)) << 3);
  int aoff[4], boff[4];
  #pragma unroll
  for (int m = 0; m < 4; ++m) aoff[m] = (wm * 64 + m * 16 + lr) * 32 + fx;
  #pragma unroll
  for (int n = 0; n < 4; ++n) boff[n] = (wn * 64 + n * 16 + lr) * 32 + fx;

  f32x4 acc[4][4];
  const f32x4 zero = {0.f, 0.f, 0.f, 0.f};
  #pragma unroll
  for (int m = 0; m < 4; ++m)
    #pragma unroll
    for (int n = 0; n < 4; ++n) acc[m][n] = zero;

  const int KT = K >> 5;
  // prologue: stage tiles 0,1,2
  #pragma unroll
  for (int t = 0; t < 3; ++t){
    GLOAD16(pa0, As + t * aStr + aW0);
    GLOAD16(pa1, As + t * aStr + aW1);
    GLOAD16(pb0, Bs + t * bStr + bW);
    pa0 += 32; pa1 += 32; pb0 += 32;
  }
  int c = 0;

  for (int kt = 0; kt < KT; ++kt){
    if (kt < KT - 2)       asm volatile("s_waitcnt vmcnt(6)" ::: "memory");
    else if (kt == KT - 2) asm volatile("s_waitcnt vmcnt(3)" ::: "memory");
    else                   asm volatile("s_waitcnt vmcnt(0)" ::: "memory");
    __builtin_amdgcn_s_barrier();            // tile kt visible to all waves

    const unsigned short* aC = As + c * aStr;
    const unsigned short* bC = Bs + c * bStr;
    bf16x8 af[4], bf[4];
    #pragma unroll
    for (int m = 0; m < 4; ++m) af[m] = *(const bf16x8*)(aC + aoff[m]);
    #pragma unroll
    for (int n = 0; n < 4; ++n) bf[n] = *(const bf16x8*)(bC + boff[n]);

    asm volatile("s_waitcnt lgkmcnt(0)" ::: "memory");
    __builtin_amdgcn_sched_barrier(0);       // rule #18
    __builtin_amdgcn_s_barrier();            // all waves done reading buf c

    if (kt + 3 < KT){                        // refill buf c with tile kt+3
      GLOAD16(pa0, As + c * aStr + aW0);
      GLOAD16(pa1, As + c * aStr + aW1);
      GLOAD16(pb0, Bs + c * bStr + bW);
      pa0 += 32; pa1 += 32; pb0 += 32;
    }

    #pragma unroll
    for (int n = 0; n < 4; ++n)
      #pragma unroll
      for (int m = 0; m < 4; ++m)
        acc[m][n] = __builtin_amdgcn_mfma_f32_16x16x32_bf16(af[m], bf[n], acc[m][n], 0, 0, 0);

    c = (c == 2) ? 0 : c + 1;
  }

  // ---- epilogue: C/D col = lane&15, row = (lane>>4)*4 + reg ----
  const int colBase = nt * 128 + wn * 64;
  #pragma unroll
  for (int m = 0; m < 4; ++m){
    #pragma unroll
    for (int r = 0; r < 4; ++r){
      const int grow = mt * 256 + wm * 64 + m * 16 + lq * 4 + r;
      if (grow >= cntE) continue;
      const int orow = list[e * T_TOK + grow];    // slot
      unsigned short* op = Out + (size_t)orow * N + colBase;
      #pragma unroll
      for (int n = 0; n < 4; ++n) op[n * 16 + lr] = f2bf(acc[m][n][r]);
    }
  }
}

// ---- SwiGLU in place on N-concat rows: GU[r][c] = silu(GU[r][c])*GU[r][NI+c] ----
__global__ void swiglu_ip_kernel(unsigned short* __restrict__ GU, int n8, int NI8){
  const int stride = gridDim.x * blockDim.x;
  bf16x8* p = (bf16x8*)GU;
  for (int i = blockIdx.x * blockDim.x + threadIdx.x; i < n8; i += stride){
    const int r = i / NI8, ccol = i - r * NI8;
    const size_t gi = (size_t)r * 2 * NI8 + ccol;
    const bf16x8 g = p[gi];
    const bf16x8 u = p[gi + NI8];
    bf16x8 h;
    #pragma unroll
    for (int j = 0; j < 8; ++j){
      const float gv = bf2f((unsigned short)g[j]);
      const float uv = bf2f((unsigned short)u[j]);
      h[j] = (short)f2bf(gv / (1.f + __expf(-gv)) * uv);
    }
    p[gi] = h;
  }
}

// ---- combine: out[t] += sum_k wslot[4t+k] * H2[4t+k] ----
__global__ void combine_kernel(const unsigned short* __restrict__ H2,
                               const float* __restrict__ wslot,
                               float* __restrict__ out){
  const int t = blockIdx.x;
  const int ccol = threadIdx.x * 8;
  float w[4];
  #pragma unroll
  for (int k = 0; k < 4; ++k) w[k] = wslot[t * 4 + k];
  float* o = out + (size_t)t * D_MODEL + ccol;
  float a[8];
  #pragma unroll
  for (int j = 0; j < 8; ++j) a[j] = o[j];
  #pragma unroll
  for (int k = 0; k < 4; ++k){
    const bf16x8 hv = *(const bf16x8*)(H2 + (size_t)(t * 4 + k) * D_MODEL + ccol);
    #pragma unroll
    for (int j = 0; j < 8; ++j) a[j] += w[k] * bf2f((unsigned short)hv[j]);
  }
  #pragma unroll
  for (int j = 0; j < 8; ++j) o[j] = a[j];
}

extern "C" void kernel_launch(void* const* d_in, const int* in_sizes, int n_in,
                              void* d_out, int out_size, void* d_ws, size_t ws_size,
                              hipStream_t stream)
{
  const float* x   = (const float*)d_in[0];
  const float* Wg  = (const float*)d_in[1];
  const float* W1  = (const float*)d_in[2];
  const float* W3  = (const float*)d_in[3];
  const float* W2  = (const float*)d_in[4];
  const float* Ws1 = (const float*)d_in[5];
  const float* Ws3 = (const float*)d_in[6];
  const float* Ws2 = (const float*)d_in[7];
  float* out = (float*)d_out;

  // ---- workspace (~430 MiB used; proven safe through R11) ----
  char* ws = (char*)d_ws;
  int*   cnt   = (int*)(ws);                     // 64 B
  int*   list  = (int*)(ws + 4096);              // 128 KiB
  float* wslot = (float*)(ws + 4096 + 131072);   // 32 KiB
  unsigned short* xbf  = (unsigned short*)(ws + MIB(1));    // 8 MiB
  unsigned short* S1   = (unsigned short*)(ws + MIB(10));   // 23 MiB: Ws1 || Ws3 concat
  unsigned short* S3   = S1 + (size_t)SH_INTER * D_MODEL;
  unsigned short* S2   = (unsigned short*)(ws + MIB(34));   // 11.5 MiB
  unsigned short* GU_s = (unsigned short*)(ws + MIB(46));   // 23.1 MiB (shared G|U)
  unsigned short* Hr   = (unsigned short*)(ws + MIB(70));   // 46.1 MiB (routed G|U concat)
  unsigned short* H2   = (unsigned short*)(ws + MIB(118));  // 33.6 MiB
  unsigned short* W1b  = (unsigned short*)(ws + MIB(152));  // 92.3 MiB
  unsigned short* W3b  = (unsigned short*)(ws + MIB(245));  // 92.3 MiB
  unsigned short* W2b  = (unsigned short*)(ws + MIB(338));  // 92.3 MiB

  const int NW_R = 16 * N_INTER * D_MODEL / 4;   // float4 per routed weight tensor

  hipMemsetAsync(cnt, 0, 4096, stream);
  cvt4_kernel<<<2048, 256, 0, stream>>>(x, Ws1, Ws3, Ws2, xbf, S1, S3, S2);
  gate_kernel<<<T_TOK, 64, 0, stream>>>(x, Wg, cnt, list, wslot);

  // shared G+U concat (N=5632): grid 16x44 = 704   [R6-proven]
  gemm6_kernel<0><<<704, 256, 0, stream>>>(xbf, S1, GU_s,
                                           2 * SH_INTER, D_MODEL, D_MODEL, 16, 44);
  swiglu_ip_kernel<<<2048, 256, 0, stream>>>(GU_s, T_TOK * SH_INTER / 8, SH_INTER / 8);

  // shared down (strided A over concat G-half) -> out (initializes d_out)
  gemm6_kernel<1><<<256, 256, 0, stream>>>(GU_s, S2, out,
                                           D_MODEL, SH_INTER, 2 * SH_INTER, 16, 16);

  // routed weights gate+up -> bf16 (standalone streaming: proven cheapest)
  cvt_bf16_kernel<<<4096, 256, 0, stream>>>(W1, W1b, NW_R);
  cvt_bf16_kernel<<<4096, 256, 0, stream>>>(W3, W3b, NW_R);

  // routed G+U merged (BM=256, dual-B panel select at NTH=11): grid 16x8x22 = 2816
  gemmW_kernel<2><<<16 * 8 * 22, 512, 0, stream>>>(xbf, W1b, W3b, Hr, list, cnt,
                                                   D_MODEL, 2 * N_INTER, D_MODEL, 22, 11);
  swiglu_ip_kernel<<<2048, 256, 0, stream>>>(Hr, NSLOT * N_INTER / 8, N_INTER / 8);

  cvt_bf16_kernel<<<4096, 256, 0, stream>>>(W2, W2b, NW_R);

  // routed down (BM=256, A = Hr strided 2*NI, gathered by slot): grid 16x8x16 = 2048
  gemmW_kernel<3><<<16 * 8 * 16, 512, 0, stream>>>(Hr, W2b, nullptr, H2, list, cnt,
                                                   N_INTER, D_MODEL, 2 * N_INTER, 16, 0);

  combine_kernel<<<T_TOK, 256, 0, stream>>>(H2, wslot, out);
}

// Round 13
// 624.656 us; speedup vs baseline: 1.0993x; 1.0993x over previous
//
#include <hip/hip_runtime.h>
#include <stdint.h>

// ---- problem constants ----
#define D_MODEL  2048
#define N_INTER  1408
#define SH_INTER 2816
#define T_TOK    2048
#define NSLOT    (T_TOK * 4)
#define MIB(x)   ((size_t)(x) << 20)

typedef __attribute__((ext_vector_type(8))) short bf16x8;
typedef __attribute__((ext_vector_type(4))) float f32x4;

__device__ __forceinline__ unsigned short f2bf(float f){
  unsigned int b = __builtin_bit_cast(unsigned int, f);
  b = (b + 0x7FFFu + ((b >> 16) & 1u)) >> 16;   // RNE, finite inputs
  return (unsigned short)b;
}
__device__ __forceinline__ float bf2f(unsigned short h){
  unsigned int b = ((unsigned int)h) << 16;
  return __builtin_bit_cast(float, b);
}

// async global->LDS, 16B per lane; LDS dest = wave-uniform base + lane*16
#define GLOAD16(gp, lp) __builtin_amdgcn_global_load_lds( \
    (const __attribute__((address_space(1))) unsigned int*)(gp), \
    (__attribute__((address_space(3))) unsigned int*)(lp), 16, 0, 0)

// ---------------- fp32 -> bf16 streaming convert ----------------
__global__ void cvt_bf16_kernel(const float* __restrict__ x,
                                unsigned short* __restrict__ o, int n4){
  const int stride = gridDim.x * blockDim.x;
  for (int i = blockIdx.x * blockDim.x + threadIdx.x; i < n4; i += stride){
    const float4 v = ((const float4*)x)[i];
    ushort4 u; u.x = f2bf(v.x); u.y = f2bf(v.y); u.z = f2bf(v.z); u.w = f2bf(v.w);
    ((ushort4*)o)[i] = u;
  }
}

// ---- routed-weight convert into per-expert G|U concat: dst[e][off + r] ----
__global__ void cvt_routed_kernel(const float* __restrict__ src,
                                  unsigned short* __restrict__ dst,
                                  int n4, int nik4, int off4){
  const int stride = gridDim.x * blockDim.x;
  for (int i = blockIdx.x * blockDim.x + threadIdx.x; i < n4; i += stride){
    const int e = i / nik4;
    const int r = i - e * nik4;
    const float4 v = ((const float4*)src)[i];
    ushort4 u; u.x = f2bf(v.x); u.y = f2bf(v.y); u.z = f2bf(v.z); u.w = f2bf(v.w);
    ((ushort4*)dst)[(size_t)e * 2 * nik4 + off4 + r] = u;
  }
}

// ---------------- phase A: convert x + all shared-expert weights ----------------
// S1 and S3 CONTIGUOUS (S3 = S1 + SH_INTER*D_MODEL) forming the shared G|U concat.
__global__ void cvt4_kernel(const float* __restrict__ x,  const float* __restrict__ Ws1,
                            const float* __restrict__ Ws3, const float* __restrict__ Ws2,
                            unsigned short* __restrict__ xbf, unsigned short* __restrict__ S1,
                            unsigned short* __restrict__ S3,  unsigned short* __restrict__ S2){
  const int N0 = T_TOK * D_MODEL / 4;
  const int NW = SH_INTER * D_MODEL / 4;
  const int total = N0 + 3 * NW;
  const int stride = gridDim.x * blockDim.x;
  for (int i = blockIdx.x * blockDim.x + threadIdx.x; i < total; i += stride){
    const float4* s; ushort4* d; int j;
    if (i < N0)            { s = (const float4*)x;   d = (ushort4*)xbf; j = i; }
    else if (i < N0 + NW)  { s = (const float4*)Ws1; d = (ushort4*)S1;  j = i - N0; }
    else if (i < N0 + 2*NW){ s = (const float4*)Ws3; d = (ushort4*)S3;  j = i - N0 - NW; }
    else                   { s = (const float4*)Ws2; d = (ushort4*)S2;  j = i - N0 - 2*NW; }
    const float4 v = s[j];
    ushort4 u; u.x = f2bf(v.x); u.y = f2bf(v.y); u.z = f2bf(v.z); u.w = f2bf(v.w);
    d[j] = u;
  }
}

// ---------------- gate: softmax + group-limited top-k ----------------
__global__ void gate_kernel(const float* __restrict__ x, const float* __restrict__ Wg,
                            int* __restrict__ cnt, int* __restrict__ list,
                            float* __restrict__ wslot){
  const int t = blockIdx.x;
  const int l = threadIdx.x;
  const int e = l & 15, q = l >> 4;
  const float* xr = x + (size_t)t * D_MODEL + q * 512;
  const float* wr = Wg + (size_t)e * D_MODEL + q * 512;
  float p = 0.f;
  #pragma unroll 4
  for (int i = 0; i < 512; i += 4){
    float4 xv = *(const float4*)(xr + i);
    float4 wv = *(const float4*)(wr + i);
    p += xv.x*wv.x + xv.y*wv.y + xv.z*wv.z + xv.w*wv.w;
  }
  p += __shfl_xor(p, 16);
  p += __shfl_xor(p, 32);
  float mx = p;
  for (int d = 1; d < 16; d <<= 1) mx = fmaxf(mx, __shfl_xor(mx, d));
  float ex = __expf(p - mx);
  float sum = ex;
  for (int d = 1; d < 16; d <<= 1) sum += __shfl_xor(sum, d);
  const float sc = ex / sum;
  float gm = fmaxf(sc, __shfl_xor(sc, 1));
  gm = fmaxf(gm, __shfl_xor(gm, 2));
  const float g0 = __shfl(gm, 0), g1 = __shfl(gm, 4),
              g2 = __shfl(gm, 8), g3 = __shfl(gm, 12);
  const int grp = e >> 2;
  const float gs[4] = {g0, g1, g2, g3};
  int grank = 0;
  #pragma unroll
  for (int j = 0; j < 4; ++j)
    if (gs[j] > gm || (gs[j] == gm && j < grp)) grank++;
  const float msc = (grank < 2) ? sc : -INFINITY;
  int erank = 0;
  #pragma unroll
  for (int j = 0; j < 16; ++j){
    const float oj = __shfl(msc, j);
    if (oj > msc || (oj == msc && j < e)) erank++;
  }
  if (q == 0 && erank < 4 && msc > -INFINITY){
    const int pos = atomicAdd(&cnt[e], 1);
    const int slot = (t << 2) | erank;
    list[e * T_TOK + pos] = slot;
    wslot[slot] = sc;            // ROUTE_SCALE = 1
  }
}

// ==== 8-phase 256x256xBK64 GEMM: 8 waves (2M x 4N), per-wave 128x64 ====
// K-tile = 64, staged as 4 units {A-kh0, B-kh0, A-kh1, B-kh1} of 16KB
// (2 global_load_lds per wave per unit). Per tile 4 phases (kh x mh), each:
// [vmcnt(4) at p0/p2] barrier / ds_read quadrant / issue unit p of tile t+1 /
// lgkmcnt(0)+sched_barrier / setprio(1) 16xMFMA setprio(0) / barrier.
// Steady-state waits NEVER drain (T4); LDS 128KB dbuf; XOR swizzle (R4-proven).
// MODE 0: linear A, bf16 out rows      MODE 1: linear A, fp32 out + ks panel
// MODE 2: A by token (list>>2), bf16 out at slot
// MODE 3: A by slot (list), bf16 out at slot
template<int MODE, int KS>
__global__ __launch_bounds__(512, 1)
void gemm8p_kernel(const unsigned short* __restrict__ A,
                   const unsigned short* __restrict__ B,
                   void* __restrict__ OutP,
                   const int* __restrict__ list,
                   const int* __restrict__ cnt,
                   int K, int N, int Astride, size_t eBstride,
                   int MT, int NT)
{
  constexpr bool GATHER = (MODE == 2 || MODE == 3);
  __shared__ unsigned short LDS[65536];   // 128 KB: [buf 32768 sh][A 16384 | B 16384]

  // bijective XCD-chunked swizzle (all grids % 8 == 0)
  const int per = gridDim.x >> 3;
  const int gsw = (blockIdx.x & 7) * per + (blockIdx.x >> 3);
  const int mt = gsw % MT;
  int rest = gsw / MT;
  const int nt = rest % NT; rest /= NT;
  const int ks = (KS > 1) ? (rest % KS) : 0;
  const int e  = GATHER ? ((KS > 1) ? rest / KS : rest) : 0;
  const int cntE = GATHER ? cnt[e] : (MT * 256);
  if (mt * 256 >= cntE) return;

  const int tid = threadIdx.x, wid = tid >> 6, lane = tid & 63;
  const int kOff = (KS > 1) ? ks * (K / KS) : 0;
  const int sx = ((lane & 3) ^ ((lane >> 3) & 3)) << 3;   // src 16B-slot XOR, shorts

  // ---- staging sources: wave wid, j=0/1 -> 16-row group (2*wid+j) ----
  const unsigned short* pa[2];
  const unsigned short* pb[2];
  const unsigned short* Bb = B + (GATHER ? (size_t)e * eBstride : 0);
  #pragma unroll
  for (int j = 0; j < 2; ++j){
    const int rl = (2 * wid + j) * 16 + (lane >> 2);   // tile-local row
    int ga;
    if (GATHER){
      int p = mt * 256 + rl;
      const int lim = cntE - 1;
      p = p < lim ? p : lim;
      const int en = list[e * T_TOK + p];
      ga = (MODE == 2) ? (en >> 2) : en;
    } else ga = mt * 256 + rl;
    pa[j] = A + (size_t)ga * Astride + kOff + sx;
    pb[j] = Bb + (size_t)(nt * 256 + rl) * K + kOff + sx;
  }
  const int dW0 = (2 * wid) * 512, dW1 = dW0 + 512;   // shorts, per-wave LDS dest

  // ---- fragment read offsets (XOR-swizzled; unit-local, row stride 32 sh) ----
  const int wm = wid >> 2, wn = wid & 3, lr = lane & 15, lq = lane >> 4;
  const int fx = (lq ^ ((lr >> 1) & 3)) << 3;
  int aoff0[4], aoff1[4], boff[4];
  #pragma unroll
  for (int m = 0; m < 4; ++m){
    aoff0[m] = (wm * 128 + m * 16 + lr) * 32 + fx;          // mh=0
    aoff1[m] = (wm * 128 + 64 + m * 16 + lr) * 32 + fx;     // mh=1
  }
  #pragma unroll
  for (int n = 0; n < 4; ++n) boff[n] = 16384 + (wn * 64 + n * 16 + lr) * 32 + fx;

  f32x4 acc[8][4];
  const f32x4 zero = {0.f, 0.f, 0.f, 0.f};
  #pragma unroll
  for (int M = 0; M < 8; ++M)
    #pragma unroll
    for (int n = 0; n < 4; ++n) acc[M][n] = zero;

  const int KT = (K / (KS > 1 ? KS : 1)) >> 6;   // tiles of 64

  // ---- prologue: tile 0's 4 units in steady-state order A0,B0,A1,B1 ----
  GLOAD16(pa[0],      &LDS[dW0]);
  GLOAD16(pa[1],      &LDS[dW1]);
  GLOAD16(pb[0],      &LDS[16384 + dW0]);
  GLOAD16(pb[1],      &LDS[16384 + dW1]);
  GLOAD16(pa[0] + 32, &LDS[8192 + dW0]);
  GLOAD16(pa[1] + 32, &LDS[8192 + dW1]);
  GLOAD16(pb[0] + 32, &LDS[16384 + 8192 + dW0]);
  GLOAD16(pb[1] + 32, &LDS[16384 + 8192 + dW1]);

  for (int t = 0; t < KT; ++t){
    const int bb = (t & 1) << 15;            // buf base (shorts)
    const int db = bb ^ 32768;               // next-buf base
    const bool more = (t + 1) < KT;
    const size_t ko = (size_t)(t + 1) * 64;  // next tile k offset (shorts)
    bf16x8 af[4], bq[4];

    // ---------- phase 0: kh=0, mh=0 ----------
    asm volatile("s_waitcnt vmcnt(4)" ::: "memory");
    __builtin_amdgcn_s_barrier();
    #pragma unroll
    for (int m = 0; m < 4; ++m) af[m] = *(const bf16x8*)(&LDS[bb + aoff0[m]]);
    #pragma unroll
    for (int n = 0; n < 4; ++n) bq[n] = *(const bf16x8*)(&LDS[bb + boff[n]]);
    if (more){ GLOAD16(pa[0] + ko, &LDS[db + dW0]); GLOAD16(pa[1] + ko, &LDS[db + dW1]); }
    asm volatile("s_waitcnt lgkmcnt(0)" ::: "memory");
    __builtin_amdgcn_sched_barrier(0);
    __builtin_amdgcn_s_setprio(1);
    #pragma unroll
    for (int n = 0; n < 4; ++n)
      #pragma unroll
      for (int m = 0; m < 4; ++m)
        acc[m][n] = __builtin_amdgcn_mfma_f32_16x16x32_bf16(af[m], bq[n], acc[m][n], 0, 0, 0);
    __builtin_amdgcn_s_setprio(0);
    __builtin_amdgcn_s_barrier();

    // ---------- phase 1: kh=0, mh=1 (reuses bq) ----------
    #pragma unroll
    for (int m = 0; m < 4; ++m) af[m] = *(const bf16x8*)(&LDS[bb + aoff1[m]]);
    if (more){ GLOAD16(pb[0] + ko, &LDS[db + 16384 + dW0]);
               GLOAD16(pb[1] + ko, &LDS[db + 16384 + dW1]); }
    asm volatile("s_waitcnt lgkmcnt(0)" ::: "memory");
    __builtin_amdgcn_sched_barrier(0);
    __builtin_amdgcn_s_setprio(1);
    #pragma unroll
    for (int n = 0; n < 4; ++n)
      #pragma unroll
      for (int m = 0; m < 4; ++m)
        acc[4 + m][n] = __builtin_amdgcn_mfma_f32_16x16x32_bf16(af[m], bq[n], acc[4 + m][n], 0, 0, 0);
    __builtin_amdgcn_s_setprio(0);
    __builtin_amdgcn_s_barrier();

    // ---------- phase 2: kh=1, mh=0 ----------
    if (more) asm volatile("s_waitcnt vmcnt(4)" ::: "memory");
    else      asm volatile("s_waitcnt vmcnt(0)" ::: "memory");
    __builtin_amdgcn_s_barrier();
    #pragma unroll
    for (int m = 0; m < 4; ++m) af[m] = *(const bf16x8*)(&LDS[bb + 8192 + aoff0[m]]);
    #pragma unroll
    for (int n = 0; n < 4; ++n) bq[n] = *(const bf16x8*)(&LDS[bb + 8192 + boff[n]]);
    if (more){ GLOAD16(pa[0] + ko + 32, &LDS[db + 8192 + dW0]);
               GLOAD16(pa[1] + ko + 32, &LDS[db + 8192 + dW1]); }
    asm volatile("s_waitcnt lgkmcnt(0)" ::: "memory");
    __builtin_amdgcn_sched_barrier(0);
    __builtin_amdgcn_s_setprio(1);
    #pragma unroll
    for (int n = 0; n < 4; ++n)
      #pragma unroll
      for (int m = 0; m < 4; ++m)
        acc[m][n] = __builtin_amdgcn_mfma_f32_16x16x32_bf16(af[m], bq[n], acc[m][n], 0, 0, 0);
    __builtin_amdgcn_s_setprio(0);
    __builtin_amdgcn_s_barrier();

    // ---------- phase 3: kh=1, mh=1 (reuses bq) ----------
    #pragma unroll
    for (int m = 0; m < 4; ++m) af[m] = *(const bf16x8*)(&LDS[bb + 8192 + aoff1[m]]);
    if (more){ GLOAD16(pb[0] + ko + 32, &LDS[db + 16384 + 8192 + dW0]);
               GLOAD16(pb[1] + ko + 32, &LDS[db + 16384 + 8192 + dW1]); }
    asm volatile("s_waitcnt lgkmcnt(0)" ::: "memory");
    __builtin_amdgcn_sched_barrier(0);
    __builtin_amdgcn_s_setprio(1);
    #pragma unroll
    for (int n = 0; n < 4; ++n)
      #pragma unroll
      for (int m = 0; m < 4; ++m)
        acc[4 + m][n] = __builtin_amdgcn_mfma_f32_16x16x32_bf16(af[m], bq[n], acc[4 + m][n], 0, 0, 0);
    __builtin_amdgcn_s_setprio(0);
    __builtin_amdgcn_s_barrier();
  }

  // ---- epilogue: C/D col = lane&15, row = (lane>>4)*4 + reg ----
  const int colBase = nt * 256 + wn * 64;
  #pragma unroll
  for (int M = 0; M < 8; ++M){
    #pragma unroll
    for (int r = 0; r < 4; ++r){
      const int grow = mt * 256 + wm * 128 + (M >> 2) * 64 + (M & 3) * 16 + lq * 4 + r;
      if (MODE == 1){
        float* op = (float*)OutP + (size_t)ks * MT * 256 * N + (size_t)grow * N + colBase;
        #pragma unroll
        for (int n = 0; n < 4; ++n) op[n * 16 + lr] = acc[M][n][r];
      } else if (MODE == 0){
        unsigned short* op = (unsigned short*)OutP + (size_t)grow * N + colBase;
        #pragma unroll
        for (int n = 0; n < 4; ++n) op[n * 16 + lr] = f2bf(acc[M][n][r]);
      } else {
        if (grow >= cntE) continue;
        const int orow = list[e * T_TOK + grow];    // slot
        unsigned short* op = (unsigned short*)OutP + (size_t)orow * N + colBase;
        #pragma unroll
        for (int n = 0; n < 4; ++n) op[n * 16 + lr] = f2bf(acc[M][n][r]);
      }
    }
  }
}

// ---- SwiGLU in place on N-concat rows: GU[r][c] = silu(GU[r][c])*GU[r][NI+c] ----
__global__ void swiglu_ip_kernel(unsigned short* __restrict__ GU, int n8, int NI8){
  const int stride = gridDim.x * blockDim.x;
  bf16x8* p = (bf16x8*)GU;
  for (int i = blockIdx.x * blockDim.x + threadIdx.x; i < n8; i += stride){
    const int r = i / NI8, ccol = i - r * NI8;
    const size_t gi = (size_t)r * 2 * NI8 + ccol;
    const bf16x8 g = p[gi];
    const bf16x8 u = p[gi + NI8];
    bf16x8 h;
    #pragma unroll
    for (int j = 0; j < 8; ++j){
      const float gv = bf2f((unsigned short)g[j]);
      const float uv = bf2f((unsigned short)u[j]);
      h[j] = (short)f2bf(gv / (1.f + __expf(-gv)) * uv);
    }
    p[gi] = h;
  }
}

// ---- combine: out[t] = sum_{p<4} P[p][t] + sum_k wslot[4t+k] * H2[4t+k] ----
__global__ void combine_kernel(const unsigned short* __restrict__ H2,
                               const float* __restrict__ P,
                               const float* __restrict__ wslot,
                               float* __restrict__ out){
  const int t = blockIdx.x;
  const int ccol = threadIdx.x * 8;
  float w[4];
  #pragma unroll
  for (int k = 0; k < 4; ++k) w[k] = wslot[t * 4 + k];
  float a[8];
  #pragma unroll
  for (int j = 0; j < 8; ++j) a[j] = 0.f;
  #pragma unroll
  for (int p = 0; p < 4; ++p){
    const float* pp = P + (size_t)(p * T_TOK + t) * D_MODEL + ccol;
    #pragma unroll
    for (int j = 0; j < 8; ++j) a[j] += pp[j];
  }
  #pragma unroll
  for (int k = 0; k < 4; ++k){
    const bf16x8 hv = *(const bf16x8*)(H2 + (size_t)(t * 4 + k) * D_MODEL + ccol);
    #pragma unroll
    for (int j = 0; j < 8; ++j) a[j] += w[k] * bf2f((unsigned short)hv[j]);
  }
  float* o = out + (size_t)t * D_MODEL + ccol;
  #pragma unroll
  for (int j = 0; j < 8; ++j) o[j] = a[j];
}

extern "C" void kernel_launch(void* const* d_in, const int* in_sizes, int n_in,
                              void* d_out, int out_size, void* d_ws, size_t ws_size,
                              hipStream_t stream)
{
  const float* x   = (const float*)d_in[0];
  const float* Wg  = (const float*)d_in[1];
  const float* W1  = (const float*)d_in[2];
  const float* W3  = (const float*)d_in[3];
  const float* W2  = (const float*)d_in[4];
  const float* Ws1 = (const float*)d_in[5];
  const float* Ws3 = (const float*)d_in[6];
  const float* Ws2 = (const float*)d_in[7];
  float* out = (float*)d_out;

  // ---- workspace (~500 MiB; harness poison shows ws ~700 MiB, R10 used 534) ----
  char* ws = (char*)d_ws;
  int*   cnt   = (int*)(ws);                     // 64 B
  int*   list  = (int*)(ws + 4096);              // 128 KiB
  float* wslot = (float*)(ws + 4096 + 131072);   // 32 KiB
  unsigned short* xbf  = (unsigned short*)(ws + MIB(1));    // 8 MiB
  unsigned short* S1   = (unsigned short*)(ws + MIB(10));   // 23.1 MiB: Ws1 || Ws3
  unsigned short* S3   = S1 + (size_t)SH_INTER * D_MODEL;
  unsigned short* S2   = (unsigned short*)(ws + MIB(34));   // 11.5 MiB
  unsigned short* GU_s = (unsigned short*)(ws + MIB(46));   // 23.1 MiB (shared G|U)
  unsigned short* Hr   = (unsigned short*)(ws + MIB(70));   // 46.1 MiB (routed G|U)
  unsigned short* H2   = (unsigned short*)(ws + MIB(118));  // 33.6 MiB
  float*          P    = (float*)        (ws + MIB(152));   // 67.1 MiB (4 partials)
  unsigned short* WGU  = (unsigned short*)(ws + MIB(220));  // 184.5 MiB ([e][W1|W3])
  unsigned short* W2b  = (unsigned short*)(ws + MIB(405));  // 92.3 MiB
  const int NW_R  = 16 * N_INTER * D_MODEL / 4;   // float4 per routed tensor
  const int NIK4  = N_INTER * D_MODEL / 4;        // float4 per expert per tensor

  hipMemsetAsync(cnt, 0, 4096, stream);
  cvt4_kernel<<<2048, 256, 0, stream>>>(x, Ws1, Ws3, Ws2, xbf, S1, S3, S2);
  gate_kernel<<<T_TOK, 64, 0, stream>>>(x, Wg, cnt, list, wslot);

  // shared GU (single-B concat): M=2048, N=5632, K=2048 ; grid 8x22=176
  gemm8p_kernel<0, 1><<<176, 512, 0, stream>>>(
      xbf, S1, GU_s, nullptr, nullptr,
      D_MODEL, 2 * SH_INTER, D_MODEL, 0, 8, 22);
  swiglu_ip_kernel<<<2048, 256, 0, stream>>>(GU_s, T_TOK * SH_INTER / 8, SH_INTER / 8);

  // shared down (K-split x4 -> fp32 partials): M=2048, N=2048, K=2816 ; grid 8x8x4=256
  gemm8p_kernel<1, 4><<<256, 512, 0, stream>>>(
      GU_s, S2, P, nullptr, nullptr,
      SH_INTER, D_MODEL, 2 * SH_INTER, 0, 8, 8);

  // routed weights -> per-expert G|U concat WGU[e] = [W1[e]; W3[e]]
  cvt_routed_kernel<<<4096, 256, 0, stream>>>(W1, WGU, NW_R, NIK4, 0);
  cvt_routed_kernel<<<4096, 256, 0, stream>>>(W3, WGU, NW_R, NIK4, NIK4);

  // routed GU (token-gather): N=2816, K=2048 -> Hr[slot] ; grid 8x11x16=1408
  gemm8p_kernel<2, 1><<<1408, 512, 0, stream>>>(
      xbf, WGU, Hr, list, cnt,
      D_MODEL, 2 * N_INTER, D_MODEL, (size_t)2 * N_INTER * D_MODEL, 8, 11);
  swiglu_ip_kernel<<<2048, 256, 0, stream>>>(Hr, NSLOT * N_INTER / 8, N_INTER / 8);

  cvt_bf16_kernel<<<4096, 256, 0, stream>>>(W2, W2b, NW_R);

  // routed down (slot-gather, A = Hr strided 2*NI): N=2048, K=1408 ; grid 8x8x16=1024
  gemm8p_kernel<3, 1><<<1024, 512, 0, stream>>>(
      Hr, W2b, H2, list, cnt,
      N_INTER, D_MODEL, 2 * N_INTER, (size_t)D_MODEL * N_INTER, 8, 8);

  combine_kernel<<<T_TOK, 256, 0, stream>>>(H2, P, wslot, out);
}